// Round 1
// baseline (276.369 us; speedup 1.0000x reference)
//
#include <hip/hip_runtime.h>
#include <math.h>

#define BB 16
#define CC 512
#define NTOK 4096   // h*w = 64*64
#define SS 8

// ---------------------------------------------------------------------------
// Kernel 1: logits[b][n][s] = sum_c x[b][c][n] * Wk[s][c]
// grid = BB * (NTOK/256) = 256 blocks, 256 threads.
// tn = tid&63 owns 4 consecutive tokens (float4 loads); tc = tid>>6 owns a
// 4-way split of c. Partial sums reduced through LDS (stride-33 padding ->
// conflict-free reduction reads).
// ---------------------------------------------------------------------------
__global__ __launch_bounds__(256) void k_logits(const float* __restrict__ x,
                                                const float* __restrict__ Wk,
                                                float* __restrict__ logits) {
    __shared__ float wkT[CC * SS];           // [c][s], 16 KB
    __shared__ float red[4 * 64 * 33];       // [tc][tn*33 + i*8 + s], ~33 KB
    const int tid   = threadIdx.x;
    const int tn    = tid & 63;
    const int tc    = tid >> 6;              // 0..3
    const int blk   = blockIdx.x;
    const int b     = blk >> 4;
    const int ntile = blk & 15;
    const int n0    = ntile * 256 + tn * 4;

    // stage Wk transposed: Wk is [S][C] row-major -> wkT[c*8+s]
    for (int k = tid; k < CC * SS; k += 256) {
        int s = k >> 9;          // /512
        int c = k & (CC - 1);
        wkT[c * SS + s] = Wk[k];
    }
    __syncthreads();

    float acc[4][SS];
#pragma unroll
    for (int i = 0; i < 4; ++i)
#pragma unroll
        for (int s = 0; s < SS; ++s) acc[i][s] = 0.f;

    const float* xb = x + (size_t)b * CC * NTOK + n0;
#pragma unroll 4
    for (int k = 0; k < CC / 4; ++k) {
        int c = tc + k * 4;
        float4 x4 = *(const float4*)(xb + (size_t)c * NTOK);
        const float* wk = &wkT[c * SS];
#pragma unroll
        for (int s = 0; s < SS; ++s) {
            float w = wk[s];
            acc[0][s] += x4.x * w;
            acc[1][s] += x4.y * w;
            acc[2][s] += x4.z * w;
            acc[3][s] += x4.w * w;
        }
    }

    // write partials: thread region padded to 33 floats -> consecutive banks
    float* myred = &red[tc * (64 * 33) + tn * 33];
#pragma unroll
    for (int i = 0; i < 4; ++i)
#pragma unroll
        for (int s = 0; s < SS; ++s) myred[i * 8 + s] = acc[i][s];
    __syncthreads();

    // reduce: 2048 outputs (256 tokens x 8 s), 256 threads, 8 each at stride 256
    float* outb = logits + ((size_t)b * NTOK + (size_t)ntile * 256) * SS;
#pragma unroll
    for (int j = 0; j < 8; ++j) {
        int flat = tid + j * 256;        // = n_local*8 + s
        int tnp  = flat >> 5;            // token-group (4 tokens = 32 floats)
        int rem  = flat & 31;            // i*8+s within group
        float v = 0.f;
#pragma unroll
        for (int t = 0; t < 4; ++t) v += red[t * (64 * 33) + tnp * 33 + rem];
        outb[flat] = v;                  // consecutive tid -> coalesced
    }
}

// ---------------------------------------------------------------------------
// Kernel 2: per-(b,s) softmax stats over n: m = max_n logits, l = sum_n exp(.-m)
// grid = BB*SS = 128 blocks, 256 threads. ml[0..127]=m, ml[128..255]=l.
// ---------------------------------------------------------------------------
__global__ __launch_bounds__(256) void k_stats(const float* __restrict__ logits,
                                               float* __restrict__ ml) {
    const int b   = blockIdx.x >> 3;
    const int s   = blockIdx.x & 7;
    const int tid = threadIdx.x;

    float v[16];
    const float* base = logits + (size_t)b * NTOK * SS + s;
#pragma unroll
    for (int j = 0; j < 16; ++j) v[j] = base[(size_t)(tid + j * 256) * SS];

    float m = v[0];
#pragma unroll
    for (int j = 1; j < 16; ++j) m = fmaxf(m, v[j]);
#pragma unroll
    for (int off = 32; off > 0; off >>= 1) m = fmaxf(m, __shfl_down(m, off, 64));

    __shared__ float sm[4];
    __shared__ float sl[4];
    const int wave = tid >> 6;
    const int lane = tid & 63;
    if (lane == 0) sm[wave] = m;
    __syncthreads();
    const float mm = fmaxf(fmaxf(sm[0], sm[1]), fmaxf(sm[2], sm[3]));

    float l = 0.f;
#pragma unroll
    for (int j = 0; j < 16; ++j) l += __expf(v[j] - mm);
#pragma unroll
    for (int off = 32; off > 0; off >>= 1) l += __shfl_down(l, off, 64);
    if (lane == 0) sl[wave] = l;
    __syncthreads();
    if (tid == 0) {
        ml[blockIdx.x]       = mm;
        ml[128 + blockIdx.x] = sl[0] + sl[1] + sl[2] + sl[3];
    }
}

// ---------------------------------------------------------------------------
// Kernel 3: w[n,s] = softmax/l1-renorm; out[b,c,n] = relu(x + sum_s w*Wv[c,s])
// grid = BB * (NTOK/256) * 2 = 512 blocks, 256 threads.
// tn owns 4 tokens (float4), tc 4-way c split, c-range halved across blocks.
// ---------------------------------------------------------------------------
__global__ __launch_bounds__(256) void k_out(const float* __restrict__ x,
                                             const float* __restrict__ Wv,
                                             const float* __restrict__ logits,
                                             const float* __restrict__ ml,
                                             float* __restrict__ out) {
    __shared__ float wv[CC * SS];            // natural [c][s] layout, 16 KB
    const int tid   = threadIdx.x;
    const int tn    = tid & 63;
    const int tc    = tid >> 6;              // 0..3
    const int blk   = blockIdx.x;
    const int b     = blk >> 5;
    const int rest  = blk & 31;
    const int ntile = rest >> 1;
    const int chalf = rest & 1;
    const int n0    = ntile * 256 + tn * 4;

    for (int k = tid; k < CC * SS; k += 256) wv[k] = Wv[k];  // same flat layout

    float m[SS], invl[SS];
    const float* mb = ml + b * SS;
#pragma unroll
    for (int s = 0; s < SS; ++s) {
        m[s]    = mb[s];
        invl[s] = 1.0f / mb[128 + s];
    }

    // logits for this thread's 4 tokens: 32 consecutive floats
    const float* lg = logits + ((size_t)b * NTOK + n0) * SS;
    float w[4][SS];
#pragma unroll
    for (int i = 0; i < 4; ++i) {
        float4 p0 = *(const float4*)(lg + i * 8);
        float4 p1 = *(const float4*)(lg + i * 8 + 4);
        float e[SS] = {p0.x, p0.y, p0.z, p0.w, p1.x, p1.y, p1.z, p1.w};
        float rs = 0.f;
#pragma unroll
        for (int s = 0; s < SS; ++s) {
            float p = __expf(e[s] - m[s]) * invl[s];
            w[i][s] = p;
            rs += p;
        }
        float inv = 1.0f / (1e-9f + rs);
#pragma unroll
        for (int s = 0; s < SS; ++s) w[i][s] *= inv;
    }
    __syncthreads();

    const size_t xbase = (size_t)b * CC * NTOK + n0;
#pragma unroll 4
    for (int k = 0; k < CC / 8; ++k) {        // 64 iters: this block's c half
        int c = chalf * 256 + tc + k * 4;
        const float* xp = x + xbase + (size_t)c * NTOK;
        float4 x4 = *(const float4*)xp;
        const float* wvc = &wv[c * SS];
        float o0 = 0.f, o1 = 0.f, o2 = 0.f, o3 = 0.f;
#pragma unroll
        for (int s = 0; s < SS; ++s) {
            float vv = wvc[s];
            o0 += w[0][s] * vv;
            o1 += w[1][s] * vv;
            o2 += w[2][s] * vv;
            o3 += w[3][s] * vv;
        }
        float4 y;
        y.x = fmaxf(x4.x + o0, 0.f);
        y.y = fmaxf(x4.y + o1, 0.f);
        y.z = fmaxf(x4.z + o2, 0.f);
        y.w = fmaxf(x4.w + o3, 0.f);
        *(float4*)(out + xbase + (size_t)c * NTOK) = y;
    }
}

// ---------------------------------------------------------------------------
extern "C" void kernel_launch(void* const* d_in, const int* in_sizes, int n_in,
                              void* d_out, int out_size, void* d_ws, size_t ws_size,
                              hipStream_t stream) {
    const float* x  = (const float*)d_in[0];   // [16][512][64][64]
    const float* Wk = (const float*)d_in[1];   // [8][512]
    const float* Wv = (const float*)d_in[2];   // [512][8]
    float* outp = (float*)d_out;

    float* logits = (float*)d_ws;                          // BB*NTOK*SS floats = 2 MB
    float* ml     = logits + (size_t)BB * NTOK * SS;       // 256 floats (m then l)

    k_logits<<<BB * (NTOK / 256), 256, 0, stream>>>(x, Wk, logits);
    k_stats<<<BB * SS, 256, 0, stream>>>(logits, ml);
    k_out<<<BB * (NTOK / 256) * 2, 256, 0, stream>>>(x, Wv, logits, ml, outp);
}